// Round 3
// baseline (557.595 us; speedup 1.0000x reference)
//
#include <hip/hip_runtime.h>
#include <stdint.h>

typedef unsigned short u16;
typedef __attribute__((ext_vector_type(8))) short short8;
typedef __attribute__((ext_vector_type(4))) float f32x4;

// ---------- bf16 helpers (RNE) ----------
static __device__ __forceinline__ u16 f2bf(float f) {
    union { float f; uint32_t u; } c; c.f = f;
    uint32_t u = c.u;
    u += 0x7FFFu + ((u >> 16) & 1u);
    return (u16)(u >> 16);
}

// ---------- problem constants ----------
#define D_IN   2048
#define D_OUT  2048
#define MTOT   32768   // B*T = 16*2048
#define RP     64      // rank padded to one BK tile
#define BK     64
#define NTM    32      // main K-tiles (2048/64)

// async global->LDS, 16B per lane; LDS dest = wavebase + lane*16 (linear)
__device__ __forceinline__ void gload16(const u16* g, u16* l) {
    __builtin_amdgcn_global_load_lds(
        (const __attribute__((address_space(1))) void*)g,
        (__attribute__((address_space(3))) void*)l, 16, 0, 0);
}

// ---------- prep: W fp32 -> bf16 ----------
__global__ __launch_bounds__(256) void k_cast_w(const float* __restrict__ W, u16* __restrict__ Wb) {
    int i = (blockIdx.x * 256 + threadIdx.x) * 8;
    const float4* p = (const float4*)(W + i);
    float4 v0 = p[0], v1 = p[1];
    short8 o;
    o[0]=f2bf(v0.x); o[1]=f2bf(v0.y); o[2]=f2bf(v0.z); o[3]=f2bf(v0.w);
    o[4]=f2bf(v1.x); o[5]=f2bf(v1.y); o[6]=f2bf(v1.z); o[7]=f2bf(v1.w);
    *(short8*)(Wb + i) = o;
}

// ---------- prep: x fp32 -> bf16, grid-stride ----------
__global__ __launch_bounds__(256) void k_cast_x(const float* __restrict__ x, u16* __restrict__ xb) {
    const size_t total = (size_t)MTOT * D_IN;
    const size_t stride = (size_t)gridDim.x * 256 * 8;
    for (size_t i = ((size_t)blockIdx.x * 256 + threadIdx.x) * 8; i < total; i += stride) {
        const float4* p = (const float4*)(x + i);
        float4 v0 = p[0], v1 = p[1];
        short8 o;
        o[0]=f2bf(v0.x); o[1]=f2bf(v0.y); o[2]=f2bf(v0.z); o[3]=f2bf(v0.w);
        o[4]=f2bf(v1.x); o[5]=f2bf(v1.y); o[6]=f2bf(v1.z); o[7]=f2bf(v1.w);
        *(short8*)(xb + i) = o;
    }
}

// ---------- prep: A (a,16,d) fp32 -> Apad (a,RP=64,d) bf16, rows 16..63 zero ----------
__global__ __launch_bounds__(256) void k_build_ap(const float* __restrict__ A, u16* __restrict__ Ap) {
    int i = blockIdx.x * 256 + threadIdx.x;   // over 8*64*2048 = 1048576
    int d = i & 2047;
    int r = (i >> 11) & 63;
    int a = i >> 17;
    float v = (r < 16) ? A[(((a << 4) + r) << 11) + d] : 0.0f;
    Ap[i] = f2bf(v);
}

// ---------- prep: Bm (a,n,16) fp32 -> Bp (a,n,RP=64) bf16, cols 16..63 zero ----------
__global__ __launch_bounds__(256) void k_build_bp(const float* __restrict__ Bm, u16* __restrict__ Bp) {
    int i = blockIdx.x * 256 + threadIdx.x;   // over 8*2048*64 = 1048576
    int j = i & 63;
    int n = (i >> 6) & 2047;
    int a = i >> 17;
    float v = (j < 16) ? Bm[((((a << 11) + n)) << 4) + j] : 0.0f;
    Bp[i] = f2bf(v);
}

// ---------- xa = s * (xb @ Apad^T) : skinny MFMA GEMM, M=32768 N=64 K=2048 ----------
__global__ __launch_bounds__(256) void k_xa(
    const u16* __restrict__ xb, const u16* __restrict__ Ap,
    const float* __restrict__ scal, const int* __restrict__ aidx,
    u16* __restrict__ xa)
{
    __shared__ __align__(16) u16 Xs[128 * BK];  // 16 KB
    __shared__ __align__(16) u16 Ps[64 * BK];   // 8 KB
    const int tid = threadIdx.x, lane = tid & 63, wid = tid >> 6;
    const int m0 = blockIdx.x << 7;
    const int a = aidx[m0 >> 11];
    const float s = scal[a];
    const int scol = ((lane & 7) ^ (lane >> 3)) << 3;   // swizzled source col (elems)
    const int wr = wid >> 1, wc = wid & 1;
    const int arow = (wr << 6) + (lane & 15);
    const int brow = (wc << 5) + (lane & 15);

    f32x4 acc[4][2];
    #pragma unroll
    for (int i = 0; i < 4; ++i) { acc[i][0] = 0.f; acc[i][1] = 0.f; }

    const u16* apg = Ap + ((size_t)a << 17);

    const u16* gX[4]; u16* lX[4];
    #pragma unroll
    for (int it = 0; it < 4; ++it) {
        const int chunk = (wid << 2) + it;
        const int row = (chunk << 3) + (lane >> 3);
        gX[it] = xb + ((size_t)(m0 + row) << 11) + scol;
        lX[it] = Xs + (chunk << 9) + (lane << 3);
    }
    const u16* gP[2]; u16* lP[2];
    #pragma unroll
    for (int it = 0; it < 2; ++it) {
        const int chunk = (wid << 1) + it;
        const int row = (chunk << 3) + (lane >> 3);
        gP[it] = apg + ((size_t)row << 11) + scol;
        lP[it] = Ps + (chunk << 9) + (lane << 3);
    }

    for (int kt = 0; kt < 32; ++kt) {
        const int k0 = kt << 6;
        #pragma unroll
        for (int it = 0; it < 4; ++it) gload16(gX[it] + k0, lX[it]);
        #pragma unroll
        for (int it = 0; it < 2; ++it) gload16(gP[it] + k0, lP[it]);
        asm volatile("s_waitcnt vmcnt(0)" ::: "memory");
        __syncthreads();
        #pragma unroll
        for (int kk = 0; kk < 2; ++kk) {
            const int ss = ((((kk << 2) + (lane >> 4)) ^ (lane & 7)) << 3);
            short8 af[4], bv[2];
            #pragma unroll
            for (int mi = 0; mi < 4; ++mi)
                af[mi] = *(const short8*)(Xs + (arow + mi * 16) * BK + ss);
            #pragma unroll
            for (int ni = 0; ni < 2; ++ni)
                bv[ni] = *(const short8*)(Ps + (brow + ni * 16) * BK + ss);
            #pragma unroll
            for (int mi = 0; mi < 4; ++mi)
                #pragma unroll
                for (int ni = 0; ni < 2; ++ni)
                    acc[mi][ni] = __builtin_amdgcn_mfma_f32_16x16x32_bf16(af[mi], bv[ni], acc[mi][ni], 0, 0, 0);
        }
        __syncthreads();
    }

    #pragma unroll
    for (int mi = 0; mi < 4; ++mi) {
        #pragma unroll
        for (int ni = 0; ni < 2; ++ni) {
            const int cc = (wc << 5) + ni * 16 + (lane & 15);
            #pragma unroll
            for (int rr = 0; rr < 4; ++rr) {
                const int mm = m0 + (wr << 6) + mi * 16 + ((lane >> 4) << 2) + rr;
                xa[((size_t)mm << 6) + cc] = f2bf(acc[mi][ni][rr] * s);
            }
        }
    }
}

// ---------- main GEMM: 256x256 tile, BK=64, 8 waves, 8-phase schedule + LoRA tail ----------
__global__ __launch_bounds__(512, 2) void k_gemm(
    const u16* __restrict__ xb, const u16* __restrict__ Wb,
    const u16* __restrict__ xa, const u16* __restrict__ Bp,
    const int* __restrict__ aidx, float* __restrict__ out)
{
    __shared__ __align__(16) u16 As[2][256 * BK];  // 2 x 32 KB
    __shared__ __align__(16) u16 Bs[2][256 * BK];  // 2 x 32 KB
    const int tid = threadIdx.x, lane = tid & 63, wid = tid >> 6;

    // XCD-aware bijective swizzle (nwg = 1024, %8 == 0); n-major within chunk
    const int nb = gridDim.x;
    const int newbid = (blockIdx.x & 7) * (nb >> 3) + (blockIdx.x >> 3);
    const int bm = newbid >> 3;                 // 128 m-tiles
    const int bn = newbid & 7;                  // 8   n-tiles
    const int m0 = bm << 8, n0 = bn << 8;
    const int wr = wid >> 2, wc = wid & 3;      // 2x4 wave grid; wave tile 128x64
    const int a = aidx[m0 >> 11];               // 256-row tile within one batch (2048%256==0)

    f32x4 acc[8][4];
    #pragma unroll
    for (int i = 0; i < 8; ++i)
        #pragma unroll
        for (int j = 0; j < 4; ++j) acc[i][j] = 0.0f;

    // staging geometry: wave w, rep j stages 8 rows (chunk = w*4+j), 1 KB linear LDS
    const int r0   = (wid << 5) + (lane >> 3);          // + j*8
    const int scol = ((lane & 7) ^ (lane >> 3)) << 3;   // pre-swizzled source col (elems)
    const int ldso = wid * 2048 + lane * 8;             // + j*512 (elems)

    // prologue: stage tile 0 -> buf 0, drain, sync
    {
        const u16* gA = xb + ((size_t)(m0 + r0) << 11) + scol;
        const u16* gB = Wb + ((size_t)(n0 + r0) << 11) + scol;
        #pragma unroll
        for (int j = 0; j < 4; ++j) {
            gload16(gA + (j << 14), &As[0][ldso + (j << 9)]);
            gload16(gB + (j << 14), &Bs[0][ldso + (j << 9)]);
        }
        asm volatile("s_waitcnt vmcnt(0)" ::: "memory");
        __syncthreads();
    }

    for (int t = 0; t <= NTM; ++t) {
        const int c = t & 1;
        // issue prefetch of tile t+1 into the other buffer (idle since last group)
        if (t < NTM) {
            const int tt = t + 1;
            const int bb = c ^ 1;
            if (tt < NTM) {
                const u16* gA = xb + ((size_t)(m0 + r0) << 11) + (tt << 6) + scol;
                const u16* gB = Wb + ((size_t)(n0 + r0) << 11) + (tt << 6) + scol;
                #pragma unroll
                for (int j = 0; j < 4; ++j) {
                    gload16(gA + (j << 14), &As[bb][ldso + (j << 9)]);
                    gload16(gB + (j << 14), &Bs[bb][ldso + (j << 9)]);
                }
            } else {
                // LoRA tail sources: xa (row stride 64), Bp[a] (row stride 64)
                const u16* gA = xa + ((size_t)(m0 + r0) << 6) + scol;
                const u16* gB = Bp + ((((size_t)a << 11) + n0 + r0) << 6) + scol;
                #pragma unroll
                for (int j = 0; j < 4; ++j) {
                    gload16(gA + (j << 9), &As[bb][ldso + (j << 9)]);
                    gload16(gB + (j << 9), &Bs[bb][ldso + (j << 9)]);
                }
            }
        }

        // 4 phases: quadrant q = (mq = q>>1, nq = q&1); 12 ds_read + 16 MFMA each
        #pragma unroll
        for (int q = 0; q < 4; ++q) {
            const int mq = q >> 1, nq = q & 1;
            short8 af[4][2], bv[2][2];
            #pragma unroll
            for (int i = 0; i < 4; ++i)
                #pragma unroll
                for (int kk = 0; kk < 2; ++kk) {
                    const int row = (wr << 7) + ((mq * 4 + i) << 4) + (lane & 15);
                    const int sl  = ((kk << 2) + (lane >> 4)) ^ (lane & 7);
                    af[i][kk] = *(const short8*)(&As[c][(row << 6) + (sl << 3)]);
                }
            #pragma unroll
            for (int i = 0; i < 2; ++i)
                #pragma unroll
                for (int kk = 0; kk < 2; ++kk) {
                    const int row = (wc << 6) + ((nq * 2 + i) << 4) + (lane & 15);
                    const int sl  = ((kk << 2) + (lane >> 4)) ^ (lane & 7);
                    bv[i][kk] = *(const short8*)(&Bs[c][(row << 6) + (sl << 3)]);
                }
            __builtin_amdgcn_s_barrier();
            asm volatile("s_waitcnt lgkmcnt(0)" ::: "memory");
            __builtin_amdgcn_sched_barrier(0);
            __builtin_amdgcn_s_setprio(1);
            #pragma unroll
            for (int kk = 0; kk < 2; ++kk)
                #pragma unroll
                for (int i = 0; i < 4; ++i)
                    #pragma unroll
                    for (int j = 0; j < 2; ++j)
                        acc[mq * 4 + i][nq * 2 + j] = __builtin_amdgcn_mfma_f32_16x16x32_bf16(
                            af[i][kk], bv[j][kk], acc[mq * 4 + i][nq * 2 + j], 0, 0, 0);
            __builtin_amdgcn_s_setprio(0);
            if (q == 3 && t < NTM)
                asm volatile("s_waitcnt vmcnt(0)" ::: "memory");  // ~4 phases of cover since issue
            __builtin_amdgcn_s_barrier();
        }
    }

    // epilogue: C row = (lane>>4)*4 + r, col = lane&15 (per 16x16 frag)
    #pragma unroll
    for (int mi = 0; mi < 8; ++mi) {
        #pragma unroll
        for (int ni = 0; ni < 4; ++ni) {
            const int nn = n0 + (wc << 6) + ni * 16 + (lane & 15);
            #pragma unroll
            for (int r = 0; r < 4; ++r) {
                const int mm = m0 + (wr << 7) + mi * 16 + ((lane >> 4) << 2) + r;
                out[((size_t)mm << 11) + nn] = acc[mi][ni][r];
            }
        }
    }
}

extern "C" void kernel_launch(void* const* d_in, const int* in_sizes, int n_in,
                              void* d_out, int out_size, void* d_ws, size_t ws_size,
                              hipStream_t stream) {
    const float* x  = (const float*)d_in[0];
    const float* W  = (const float*)d_in[1];
    const float* A  = (const float*)d_in[2];
    const float* Bm = (const float*)d_in[3];
    const float* sc = (const float*)d_in[4];
    const int* aidx = (const int*)d_in[5];
    float* out = (float*)d_out;

    // ws layout (bytes): xb 128MiB | Wb 8MiB | Apad 2MiB | Bp 2MiB | xa 4MiB = 144 MiB
    char* ws = (char*)d_ws;
    u16* xb = (u16*)(ws);
    u16* Wb = (u16*)(ws + 134217728);
    u16* Ap = (u16*)(ws + 134217728 + 8388608);
    u16* Bp = (u16*)(ws + 134217728 + 8388608 + 2097152);
    u16* xa = (u16*)(ws + 134217728 + 8388608 + 2097152 + 2097152);

    hipLaunchKernelGGL(k_build_ap, dim3(4096), dim3(256), 0, stream, A, Ap);
    hipLaunchKernelGGL(k_build_bp, dim3(4096), dim3(256), 0, stream, Bm, Bp);
    hipLaunchKernelGGL(k_cast_w,   dim3(2048), dim3(256), 0, stream, W, Wb);
    hipLaunchKernelGGL(k_cast_x,   dim3(2048), dim3(256), 0, stream, x, xb);
    hipLaunchKernelGGL(k_xa,       dim3(256),  dim3(256), 0, stream, xb, Ap, sc, aidx, xa);
    hipLaunchKernelGGL(k_gemm,     dim3(1024), dim3(512), 0, stream, xb, Wb, xa, Bp, aidx, out);
}

// Round 5
// 508.095 us; speedup vs baseline: 1.0974x; 1.0974x over previous
//
#include <hip/hip_runtime.h>
#include <stdint.h>

typedef unsigned short u16;
typedef __attribute__((ext_vector_type(4))) short s16x4;
typedef __attribute__((ext_vector_type(8))) short short8;
typedef __attribute__((ext_vector_type(4))) float f32x4;

// ---------- bf16 helpers (RNE) ----------
static __device__ __forceinline__ u16 f2bf(float f) {
    union { float f; uint32_t u; } c; c.f = f;
    uint32_t u = c.u;
    u += 0x7FFFu + ((u >> 16) & 1u);
    return (u16)(u >> 16);
}

// ---------- problem constants ----------
#define D_IN   2048
#define D_OUT  2048
#define MTOT   32768   // B*T
#define BK     64
#define NTM    32      // main K-tiles

// async global->LDS, 16B/lane; LDS dest = wavebase + lane*16 (linear)
__device__ __forceinline__ void gload16(const u16* g, u16* l) {
    __builtin_amdgcn_global_load_lds(
        (const __attribute__((address_space(1))) void*)g,
        (__attribute__((address_space(3))) void*)l, 16, 0, 0);
}

// ---------- fused tiny preps: cast W, build Apad, build Bpad ----------
__global__ __launch_bounds__(256) void k_prep(
    const float* __restrict__ W, const float* __restrict__ A, const float* __restrict__ Bm,
    u16* __restrict__ Wb, u16* __restrict__ Ap, u16* __restrict__ Bp)
{
    const int b = blockIdx.x, tid = threadIdx.x;
    if (b < 2048) {                       // W cast: 4M elems, 8/thread
        int i = (b * 256 + tid) * 8;
        const float4* p = (const float4*)(W + i);
        float4 v0 = p[0], v1 = p[1];
        short8 o;
        o[0]=f2bf(v0.x); o[1]=f2bf(v0.y); o[2]=f2bf(v0.z); o[3]=f2bf(v0.w);
        o[4]=f2bf(v1.x); o[5]=f2bf(v1.y); o[6]=f2bf(v1.z); o[7]=f2bf(v1.w);
        *(short8*)(Wb + i) = o;
    } else if (b < 6144) {                // Apad (a,64,d), rows 16..63 zero
        int i = (b - 2048) * 256 + tid;   // 1048576
        int d = i & 2047, r = (i >> 11) & 63, a = i >> 17;
        Ap[i] = (r < 16) ? f2bf(A[(((a << 4) + r) << 11) + d]) : (u16)0;
    } else {                              // Bpad (a,n,64), cols 16..63 zero
        int i = (b - 6144) * 256 + tid;   // 1048576
        int j = i & 63, n = (i >> 6) & 2047, a = i >> 17;
        Bp[i] = (j < 16) ? f2bf(Bm[((((a << 11) + n)) << 4) + j]) : (u16)0;
    }
}

// ---------- fused: x fp32 -> xb bf16 AND xa = s*(x @ Apad^T) (MFMA, reg-staged X) ----------
__global__ __launch_bounds__(256) void k_cast_x_xa(
    const float* __restrict__ x, const u16* __restrict__ Ap,
    const float* __restrict__ scal, const int* __restrict__ aidx,
    u16* __restrict__ xb, u16* __restrict__ xa)
{
    __shared__ __align__(16) u16 Xs[128 * BK];  // 16 KB, write-side swizzled
    __shared__ __align__(16) u16 Ps[64 * BK];   // 8 KB, gload-staged (src-swizzled)
    const int tid = threadIdx.x, lane = tid & 63, wid = tid >> 6;
    const int m0 = blockIdx.x << 7;
    const int a = aidx[m0 >> 11];
    const float s = scal[a];
    const int wr = wid >> 1, wc = wid & 1;
    const int arow = (wr << 6) + (lane & 15);
    const int brow = (wc << 5) + (lane & 15);
    const int scol = ((lane & 7) ^ (lane >> 3)) << 3;

    f32x4 acc[4][2];
    #pragma unroll
    for (int i = 0; i < 4; ++i) { acc[i][0] = 0.f; acc[i][1] = 0.f; }

    // X staging coords: round r covers rows r*16..r*16+15
    const int xrow_l = tid >> 4;          // 0..15
    const int xcol   = (tid & 15) << 2;   // fp32 col, step 4
    const int wslot  = (tid & 15) >> 1;   // 8-elem slot
    const int wsub   = (tid & 1) << 2;    // 0 or 4 elems within slot

    const u16* apg = Ap + ((size_t)a << 17);
    const u16* gP[2]; u16* lP[2];
    #pragma unroll
    for (int it = 0; it < 2; ++it) {
        const int chunk = (wid << 1) + it;
        const int row = (chunk << 3) + (lane >> 3);
        gP[it] = apg + ((size_t)row << 11) + scol;
        lP[it] = Ps + (chunk << 9) + (lane << 3);
    }

    for (int kt = 0; kt < NTM; ++kt) {
        const int k0 = kt << 6;
        float4 xv[8];
        #pragma unroll
        for (int r = 0; r < 8; ++r)
            xv[r] = *(const float4*)(x + ((size_t)(m0 + (r << 4) + xrow_l) << 11) + k0 + xcol);
        #pragma unroll
        for (int r = 0; r < 8; ++r) {
            const int row = (r << 4) + xrow_l;
            s16x4 c4;
            c4[0]=f2bf(xv[r].x); c4[1]=f2bf(xv[r].y); c4[2]=f2bf(xv[r].z); c4[3]=f2bf(xv[r].w);
            *(s16x4*)(Xs + (row << 6) + ((wslot ^ (row & 7)) << 3) + wsub) = c4;
            *(s16x4*)(xb + ((size_t)(m0 + row) << 11) + k0 + xcol) = c4;
        }
        gload16(gP[0] + k0, lP[0]);
        gload16(gP[1] + k0, lP[1]);
        asm volatile("s_waitcnt vmcnt(0)" ::: "memory");
        __syncthreads();
        #pragma unroll
        for (int kk = 0; kk < 2; ++kk) {
            const int sl = ((kk << 2) + (lane >> 4)) ^ (lane & 7);
            short8 af[4], bv[2];
            #pragma unroll
            for (int mi = 0; mi < 4; ++mi)
                af[mi] = *(const short8*)(Xs + ((arow + mi * 16) << 6) + (sl << 3));
            #pragma unroll
            for (int ni = 0; ni < 2; ++ni)
                bv[ni] = *(const short8*)(Ps + ((brow + ni * 16) << 6) + (sl << 3));
            #pragma unroll
            for (int mi = 0; mi < 4; ++mi)
                #pragma unroll
                for (int ni = 0; ni < 2; ++ni)
                    acc[mi][ni] = __builtin_amdgcn_mfma_f32_16x16x32_bf16(af[mi], bv[ni], acc[mi][ni], 0, 0, 0);
        }
        __syncthreads();
    }

    #pragma unroll
    for (int mi = 0; mi < 4; ++mi) {
        #pragma unroll
        for (int ni = 0; ni < 2; ++ni) {
            const int cc = (wc << 5) + ni * 16 + (lane & 15);
            #pragma unroll
            for (int rr = 0; rr < 4; ++rr) {
                const int mm = m0 + (wr << 6) + mi * 16 + ((lane >> 4) << 2) + rr;
                xa[((size_t)mm << 6) + cc] = f2bf(acc[mi][ni][rr] * s);
            }
        }
    }
}

// ---------- main GEMM: 256x256, BK=64, 8 waves; 2 phases/K-tile (kk-split, no re-reads) ----------
__global__ __launch_bounds__(512, 2) void k_gemm(
    const u16* __restrict__ xb, const u16* __restrict__ Wb,
    const u16* __restrict__ xa, const u16* __restrict__ Bp,
    const int* __restrict__ aidx, float* __restrict__ out)
{
    __shared__ __align__(16) u16 As[2][256 * BK];  // 2 x 32 KB
    __shared__ __align__(16) u16 Bs[2][256 * BK];  // 2 x 32 KB
    const int tid = threadIdx.x, lane = tid & 63, wid = tid >> 6;

    // XCD-aware bijective swizzle (1024 blocks, n-major within XCD chunk)
    const int newbid = (blockIdx.x & 7) * 128 + (blockIdx.x >> 3);
    const int bm = newbid >> 3, bn = newbid & 7;
    const int m0 = bm << 8, n0 = bn << 8;
    const int wr = wid >> 2, wc = wid & 3;          // 2M x 4N waves; wave tile 128x64
    const int a = aidx[m0 >> 11];

    f32x4 acc[8][4];
    #pragma unroll
    for (int i = 0; i < 8; ++i)
        #pragma unroll
        for (int j = 0; j < 4; ++j) acc[i][j] = 0.0f;

    const int r0   = (wid << 5) + (lane >> 3);
    const int scol = ((lane & 7) ^ (lane >> 3)) << 3;
    const int ldso = (wid << 11) + (lane << 3);

    const u16* gAb = xb + ((size_t)(m0 + r0) << 11) + scol;
    const u16* gBb = Wb + ((size_t)(n0 + r0) << 11) + scol;
    const u16* gAt = xa + ((size_t)(m0 + r0) << 6) + scol;
    const u16* gBt = Bp + ((((size_t)a << 11) + n0 + r0) << 6) + scol;

    #define STAGE(tt, bb)                                                       \
        do {                                                                    \
            if ((tt) < NTM) {                                                   \
                const u16* ga_ = gAb + ((tt) << 6);                             \
                const u16* gb_ = gBb + ((tt) << 6);                             \
                _Pragma("unroll")                                               \
                for (int j = 0; j < 4; ++j) {                                   \
                    gload16(ga_ + (j << 14), &As[bb][ldso + (j << 9)]);         \
                    gload16(gb_ + (j << 14), &Bs[bb][ldso + (j << 9)]);         \
                }                                                               \
            } else {                                                            \
                _Pragma("unroll")                                               \
                for (int j = 0; j < 4; ++j) {                                   \
                    gload16(gAt + (j << 9), &As[bb][ldso + (j << 9)]);          \
                    gload16(gBt + (j << 9), &Bs[bb][ldso + (j << 9)]);          \
                }                                                               \
            }                                                                   \
        } while (0)

    // prologue: stage tile 0 -> buf 0
    STAGE(0, 0);
    asm volatile("s_waitcnt vmcnt(0)" ::: "memory");
    __builtin_amdgcn_s_barrier();

    for (int t = 0; t <= NTM; ++t) {
        const int c = t & 1;
        const u16* pa = &As[c][0];
        const u16* pb = &Bs[c][0];

        #pragma unroll
        for (int kk = 0; kk < 2; ++kk) {
            if (kk == 0 && t < NTM) STAGE(t + 1, c ^ 1);   // earliest race-free issue

            short8 af[8], bv[4];
            #pragma unroll
            for (int mi = 0; mi < 8; ++mi) {
                const int row = (wr << 7) + (mi << 4) + (lane & 15);
                const int sl  = ((kk << 2) + (lane >> 4)) ^ (lane & 7);
                af[mi] = *(const short8*)(pa + (row << 6) + (sl << 3));
            }
            #pragma unroll
            for (int ni = 0; ni < 4; ++ni) {
                const int row = (wc << 6) + (ni << 4) + (lane & 15);
                const int sl  = ((kk << 2) + (lane >> 4)) ^ (lane & 7);
                bv[ni] = *(const short8*)(pb + (row << 6) + (sl << 3));
            }
            __builtin_amdgcn_s_barrier();
            asm volatile("s_waitcnt lgkmcnt(0)" ::: "memory");
            __builtin_amdgcn_sched_barrier(0);
            __builtin_amdgcn_s_setprio(1);
            #pragma unroll
            for (int mi = 0; mi < 8; ++mi)
                #pragma unroll
                for (int ni = 0; ni < 4; ++ni)
                    acc[mi][ni] = __builtin_amdgcn_mfma_f32_16x16x32_bf16(
                        af[mi], bv[ni], acc[mi][ni], 0, 0, 0);
            __builtin_amdgcn_s_setprio(0);
            if (kk == 1 && t < NTM)
                asm volatile("s_waitcnt vmcnt(0)" ::: "memory");  // next buf ready
            __builtin_amdgcn_s_barrier();
        }
    }
    #undef STAGE

    // epilogue: C row = (lane>>4)*4 + r, col = lane&15 per 16x16 frag
    #pragma unroll
    for (int mi = 0; mi < 8; ++mi) {
        #pragma unroll
        for (int ni = 0; ni < 4; ++ni) {
            const int nn = n0 + (wc << 6) + ni * 16 + (lane & 15);
            #pragma unroll
            for (int r = 0; r < 4; ++r) {
                const int mm = m0 + (wr << 7) + mi * 16 + ((lane >> 4) << 2) + r;
                out[((size_t)mm << 11) + nn] = acc[mi][ni][r];
            }
        }
    }
}

extern "C" void kernel_launch(void* const* d_in, const int* in_sizes, int n_in,
                              void* d_out, int out_size, void* d_ws, size_t ws_size,
                              hipStream_t stream) {
    const float* x  = (const float*)d_in[0];
    const float* W  = (const float*)d_in[1];
    const float* A  = (const float*)d_in[2];
    const float* Bm = (const float*)d_in[3];
    const float* sc = (const float*)d_in[4];
    const int* aidx = (const int*)d_in[5];
    float* out = (float*)d_out;

    // ws layout (bytes): xb 128MiB | Wb 8MiB | Apad 2MiB | Bp 2MiB | xa 4MiB = 144 MiB
    char* ws = (char*)d_ws;
    u16* xb = (u16*)(ws);
    u16* Wb = (u16*)(ws + 134217728);
    u16* Ap = (u16*)(ws + 134217728 + 8388608);
    u16* Bp = (u16*)(ws + 134217728 + 8388608 + 2097152);
    u16* xa = (u16*)(ws + 134217728 + 8388608 + 2097152 + 2097152);

    hipLaunchKernelGGL(k_prep,      dim3(10240), dim3(256), 0, stream, W, A, Bm, Wb, Ap, Bp);
    hipLaunchKernelGGL(k_cast_x_xa, dim3(256),   dim3(256), 0, stream, x, Ap, sc, aidx, xb, xa);
    hipLaunchKernelGGL(k_gemm,      dim3(1024),  dim3(512), 0, stream, xb, Wb, xa, Bp, aidx, out);
}

// Round 6
// 487.438 us; speedup vs baseline: 1.1439x; 1.0424x over previous
//
#include <hip/hip_runtime.h>
#include <stdint.h>

typedef unsigned short u16;
typedef __attribute__((ext_vector_type(4))) short s16x4;
typedef __attribute__((ext_vector_type(8))) short short8;
typedef __attribute__((ext_vector_type(4))) float f32x4;

// ---------- bf16 helpers (RNE) ----------
static __device__ __forceinline__ u16 f2bf(float f) {
    union { float f; uint32_t u; } c; c.f = f;
    uint32_t u = c.u;
    u += 0x7FFFu + ((u >> 16) & 1u);
    return (u16)(u >> 16);
}

// ---------- problem constants ----------
#define D_IN   2048
#define D_OUT  2048
#define MTOT   32768   // B*T
#define BK     64
#define NTM    32      // main K-tiles (LoRA tail = tile 32)

// async global->LDS, 16B/lane; LDS dest = wavebase + lane*16 (linear)
__device__ __forceinline__ void gload16(const u16* g, u16* l) {
    __builtin_amdgcn_global_load_lds(
        (const __attribute__((address_space(1))) void*)g,
        (__attribute__((address_space(3))) void*)l, 16, 0, 0);
}

// ---------- fused tiny preps: cast W, build Apad, build Bpad ----------
__global__ __launch_bounds__(256) void k_prep(
    const float* __restrict__ W, const float* __restrict__ A, const float* __restrict__ Bm,
    u16* __restrict__ Wb, u16* __restrict__ Ap, u16* __restrict__ Bp)
{
    const int b = blockIdx.x, tid = threadIdx.x;
    if (b < 2048) {                       // W cast: 4M elems, 8/thread
        int i = (b * 256 + tid) * 8;
        const float4* p = (const float4*)(W + i);
        float4 v0 = p[0], v1 = p[1];
        short8 o;
        o[0]=f2bf(v0.x); o[1]=f2bf(v0.y); o[2]=f2bf(v0.z); o[3]=f2bf(v0.w);
        o[4]=f2bf(v1.x); o[5]=f2bf(v1.y); o[6]=f2bf(v1.z); o[7]=f2bf(v1.w);
        *(short8*)(Wb + i) = o;
    } else if (b < 6144) {                // Apad (a,64,d), rows 16..63 zero
        int i = (b - 2048) * 256 + tid;
        int d = i & 2047, r = (i >> 11) & 63, a = i >> 17;
        Ap[i] = (r < 16) ? f2bf(A[(((a << 4) + r) << 11) + d]) : (u16)0;
    } else {                              // Bpad (a,n,64), cols 16..63 zero
        int i = (b - 6144) * 256 + tid;
        int j = i & 63, n = (i >> 6) & 2047, a = i >> 17;
        Bp[i] = (j < 16) ? f2bf(Bm[((((a << 11) + n)) << 4) + j]) : (u16)0;
    }
}

// ---------- fused: x fp32 -> xb bf16 AND xa = s*(x @ Apad^T) (MFMA, reg-staged X) ----------
__global__ __launch_bounds__(256) void k_cast_x_xa(
    const float* __restrict__ x, const u16* __restrict__ Ap,
    const float* __restrict__ scal, const int* __restrict__ aidx,
    u16* __restrict__ xb, u16* __restrict__ xa)
{
    __shared__ __align__(16) u16 Xs[128 * BK];
    __shared__ __align__(16) u16 Ps[64 * BK];
    const int tid = threadIdx.x, lane = tid & 63, wid = tid >> 6;
    const int m0 = blockIdx.x << 7;
    const int a = aidx[m0 >> 11];
    const float s = scal[a];
    const int wr = wid >> 1, wc = wid & 1;
    const int arow = (wr << 6) + (lane & 15);
    const int brow = (wc << 5) + (lane & 15);
    const int scol = ((lane & 7) ^ (lane >> 3)) << 3;

    f32x4 acc[4][2];
    #pragma unroll
    for (int i = 0; i < 4; ++i) { acc[i][0] = 0.f; acc[i][1] = 0.f; }

    const int xrow_l = tid >> 4;
    const int xcol   = (tid & 15) << 2;
    const int wslot  = (tid & 15) >> 1;
    const int wsub   = (tid & 1) << 2;

    const u16* apg = Ap + ((size_t)a << 17);
    const u16* gP[2]; u16* lP[2];
    #pragma unroll
    for (int it = 0; it < 2; ++it) {
        const int chunk = (wid << 1) + it;
        const int row = (chunk << 3) + (lane >> 3);
        gP[it] = apg + ((size_t)row << 11) + scol;
        lP[it] = Ps + (chunk << 9) + (lane << 3);
    }

    for (int kt = 0; kt < NTM; ++kt) {
        const int k0 = kt << 6;
        float4 xv[8];
        #pragma unroll
        for (int r = 0; r < 8; ++r)
            xv[r] = *(const float4*)(x + ((size_t)(m0 + (r << 4) + xrow_l) << 11) + k0 + xcol);
        #pragma unroll
        for (int r = 0; r < 8; ++r) {
            const int row = (r << 4) + xrow_l;
            s16x4 c4;
            c4[0]=f2bf(xv[r].x); c4[1]=f2bf(xv[r].y); c4[2]=f2bf(xv[r].z); c4[3]=f2bf(xv[r].w);
            *(s16x4*)(Xs + (row << 6) + ((wslot ^ (row & 7)) << 3) + wsub) = c4;
            *(s16x4*)(xb + ((size_t)(m0 + row) << 11) + k0 + xcol) = c4;
        }
        gload16(gP[0] + k0, lP[0]);
        gload16(gP[1] + k0, lP[1]);
        asm volatile("s_waitcnt vmcnt(0)" ::: "memory");
        __syncthreads();
        #pragma unroll
        for (int kk = 0; kk < 2; ++kk) {
            const int sl = ((kk << 2) + (lane >> 4)) ^ (lane & 7);
            short8 af[4], bv[2];
            #pragma unroll
            for (int mi = 0; mi < 4; ++mi)
                af[mi] = *(const short8*)(Xs + ((arow + mi * 16) << 6) + (sl << 3));
            #pragma unroll
            for (int ni = 0; ni < 2; ++ni)
                bv[ni] = *(const short8*)(Ps + ((brow + ni * 16) << 6) + (sl << 3));
            #pragma unroll
            for (int mi = 0; mi < 4; ++mi)
                #pragma unroll
                for (int ni = 0; ni < 2; ++ni)
                    acc[mi][ni] = __builtin_amdgcn_mfma_f32_16x16x32_bf16(af[mi], bv[ni], acc[mi][ni], 0, 0, 0);
        }
        __syncthreads();
    }

    #pragma unroll
    for (int mi = 0; mi < 4; ++mi) {
        #pragma unroll
        for (int ni = 0; ni < 2; ++ni) {
            const int cc = (wc << 5) + ni * 16 + (lane & 15);
            #pragma unroll
            for (int rr = 0; rr < 4; ++rr) {
                const int mm = m0 + (wr << 6) + mi * 16 + ((lane >> 4) << 2) + rr;
                xa[((size_t)mm << 6) + cc] = f2bf(acc[mi][ni][rr] * s);
            }
        }
    }
}

// ---------- main GEMM: 256x256, BK=64, 8 waves, counted-vmcnt 4-phase pipeline ----------
// LDS layout: [buf][khalf][row 0..255][32 elems], k-half = contiguous 16 KB stage unit.
__global__ __launch_bounds__(512, 2) void k_gemm(
    const u16* __restrict__ xb, const u16* __restrict__ Wb,
    const u16* __restrict__ xa, const u16* __restrict__ Bp,
    const int* __restrict__ aidx, float* __restrict__ out)
{
    __shared__ __align__(16) u16 AsF[2 * 2 * 8192];  // 64 KB
    __shared__ __align__(16) u16 BsF[2 * 2 * 8192];  // 64 KB
    const int tid = threadIdx.x, lane = tid & 63, wid = tid >> 6;

    // XCD-aware bijective swizzle (1024 blocks, n-major within XCD chunk)
    const int newbid = (blockIdx.x & 7) * 128 + (blockIdx.x >> 3);
    const int bm = newbid >> 3, bn = newbid & 7;
    const int m0 = bm << 8, n0 = bn << 8;
    const int wr = wid >> 2, wc = wid & 3;            // 2M x 4N waves; wave tile 128x64
    const int a = aidx[m0 >> 11];

    f32x4 acc[8][4];
    #pragma unroll
    for (int i = 0; i < 8; ++i)
        #pragma unroll
        for (int j = 0; j < 4; ++j) acc[i][j] = 0.0f;

    // staging: half-matrix (256 rows x 32 cols, 16 KB) = 2 gloads/thread
    const int srow  = (wid << 5) + (lane >> 2);                    // + j*16
    const int scolh = (((lane & 3) ^ ((lane >> 2) & 3)) << 3);     // swizzled src slot in k-half
    const u16* nA = xb + ((size_t)(m0 + srow) << 11) + scolh;
    const u16* nB = Wb + ((size_t)(n0 + srow) << 11) + scolh;
    const u16* lA = xa + ((size_t)(m0 + srow) << 6) + scolh;
    const u16* lB = Bp + ((((size_t)a << 11) + n0 + srow) << 6) + scolh;
    const int dbase = (wid << 10) + (lane << 3);

    // fragment read: swizzled slot within 64-B row
    const int sl8 = (((lane >> 4) ^ (lane & 3)) << 3);
    const int rla = (wr << 7) + (lane & 15);
    const int rlb = (wc << 6) + (lane & 15);

    #define VW(n) asm volatile("s_waitcnt vmcnt(" #n ")" ::: "memory")

    #define STAGE_A(tt, kh) do {                                                  \
        u16* d_ = AsF + ((((tt) & 1) << 14) | ((kh) << 13)) + dbase;              \
        if ((tt) < NTM) { const u16* g_ = nA + ((tt) << 6) + ((kh) << 5);         \
            gload16(g_, d_); gload16(g_ + (16 << 11), d_ + 512); }                \
        else { const u16* g_ = lA + ((kh) << 5);                                  \
            gload16(g_, d_); gload16(g_ + (16 << 6), d_ + 512); } } while (0)

    #define STAGE_B(tt, kh) do {                                                  \
        u16* d_ = BsF + ((((tt) & 1) << 14) | ((kh) << 13)) + dbase;              \
        if ((tt) < NTM) { const u16* g_ = nB + ((tt) << 6) + ((kh) << 5);         \
            gload16(g_, d_); gload16(g_ + (16 << 11), d_ + 512); }                \
        else { const u16* g_ = lB + ((kh) << 5);                                  \
            gload16(g_, d_); gload16(g_ + (16 << 6), d_ + 512); } } while (0)

    #define RD_A(c_, kk, mh) do {                                                 \
        _Pragma("unroll")                                                         \
        for (int mi = 0; mi < 4; ++mi) {                                          \
            const int row_ = rla + (((mh) * 4 + mi) << 4);                        \
            af_[mi] = *(const short8*)(AsF + (((c_) << 14) | ((kk) << 13)) + (row_ << 5) + sl8); } } while (0)

    #define RD_B(c_, kk) do {                                                     \
        _Pragma("unroll")                                                         \
        for (int ni = 0; ni < 4; ++ni) {                                          \
            const int row_ = rlb + (ni << 4);                                     \
            bv_[ni] = *(const short8*)(BsF + (((c_) << 14) | ((kk) << 13)) + (row_ << 5) + sl8); } } while (0)

    #define SYNC1 do { __builtin_amdgcn_s_barrier();                              \
        asm volatile("s_waitcnt lgkmcnt(0)" ::: "memory");                        \
        __builtin_amdgcn_sched_barrier(0); } while (0)

    #define MM(mh) do { __builtin_amdgcn_s_setprio(1);                            \
        _Pragma("unroll")                                                         \
        for (int mi = 0; mi < 4; ++mi)                                            \
            _Pragma("unroll")                                                     \
            for (int ni = 0; ni < 4; ++ni)                                        \
                acc[(mh) * 4 + mi][ni] = __builtin_amdgcn_mfma_f32_16x16x32_bf16( \
                    af_[mi], bv_[ni], acc[(mh) * 4 + mi][ni], 0, 0, 0);           \
        __builtin_amdgcn_s_setprio(0); } while (0)

    // 4 phases per K-tile; stage stream runs 6 phases ahead of its consumer.
    #define TILEBODY(c_, S1, S2, S3, S4) do {                                     \
        short8 af_[4], bv_[4];                                                    \
        RD_A(c_, 0, 0); RD_B(c_, 0); S1; SYNC1; MM(0); __builtin_amdgcn_s_barrier(); \
        RD_A(c_, 0, 1);              S2; SYNC1; MM(1); __builtin_amdgcn_s_barrier(); \
        RD_A(c_, 1, 0); RD_B(c_, 1); S3; SYNC1; MM(0); __builtin_amdgcn_s_barrier(); \
        RD_A(c_, 1, 1);              S4; SYNC1; MM(1); __builtin_amdgcn_s_barrier(); \
    } while (0)

    // prologue: tile0 (4 halves) + tile1 kh0 (2 halves); retire tile0-kh0, keep 8 in flight
    STAGE_A(0, 0); STAGE_B(0, 0); STAGE_A(0, 1); STAGE_B(0, 1);
    STAGE_A(1, 0); STAGE_B(1, 0);
    VW(8);
    __builtin_amdgcn_s_barrier();

    for (int t = 0; t < 31; ++t) {
        const int c_ = t & 1;
        TILEBODY(c_,
            STAGE_A(t + 1, 1),
            { STAGE_B(t + 1, 1); VW(8); },
            STAGE_A(t + 2, 0),
            { STAGE_B(t + 2, 0); VW(8); });
    }
    // t = 31 (buf1): stage LoRA kh1; no t+2; tail-adjusted waits
    TILEBODY(1,
        STAGE_A(32, 1),
        { STAGE_B(32, 1); VW(8); },
        { },
        VW(4));
    // t = 32 (LoRA tile, buf0): no stages; drain kh1 before P3
    TILEBODY(0, { }, VW(0), { }, { });

    #undef TILEBODY
    #undef MM
    #undef SYNC1
    #undef RD_B
    #undef RD_A
    #undef STAGE_B
    #undef STAGE_A
    #undef VW

    // epilogue: C row = (lane>>4)*4 + r, col = lane&15 per 16x16 frag
    #pragma unroll
    for (int mi = 0; mi < 8; ++mi) {
        #pragma unroll
        for (int ni = 0; ni < 4; ++ni) {
            const int nn = n0 + (wc << 6) + ni * 16 + (lane & 15);
            #pragma unroll
            for (int r = 0; r < 4; ++r) {
                const int mm = m0 + (wr << 7) + mi * 16 + ((lane >> 4) << 2) + r;
                out[((size_t)mm << 11) + nn] = acc[mi][ni][r];
            }
        }
    }
}

extern "C" void kernel_launch(void* const* d_in, const int* in_sizes, int n_in,
                              void* d_out, int out_size, void* d_ws, size_t ws_size,
                              hipStream_t stream) {
    const float* x  = (const float*)d_in[0];
    const float* W  = (const float*)d_in[1];
    const float* A  = (const float*)d_in[2];
    const float* Bm = (const float*)d_in[3];
    const float* sc = (const float*)d_in[4];
    const int* aidx = (const int*)d_in[5];
    float* out = (float*)d_out;

    // ws layout (bytes): xb 128MiB | Wb 8MiB | Apad 2MiB | Bp 2MiB | xa 4MiB = 144 MiB
    char* ws = (char*)d_ws;
    u16* xb = (u16*)(ws);
    u16* Wb = (u16*)(ws + 134217728);
    u16* Ap = (u16*)(ws + 134217728 + 8388608);
    u16* Bp = (u16*)(ws + 134217728 + 8388608 + 2097152);
    u16* xa = (u16*)(ws + 134217728 + 8388608 + 2097152 + 2097152);

    hipLaunchKernelGGL(k_prep,      dim3(10240), dim3(256), 0, stream, W, A, Bm, Wb, Ap, Bp);
    hipLaunchKernelGGL(k_cast_x_xa, dim3(256),   dim3(256), 0, stream, x, Ap, sc, aidx, xb, xa);
    hipLaunchKernelGGL(k_gemm,      dim3(1024),  dim3(512), 0, stream, xb, Wb, xa, Bp, aidx, out);
}